// Round 11
// baseline (108.636 us; speedup 1.0000x reference)
//
#include <hip/hip_runtime.h>

// ---------------------------------------------------------------------------
// maskselfattention: B=2, S=2048, D=1024, H=16, hd=64
// convert x,W to bf16 (W transposed) -> ONE fused QKV GEMM (z-fused: A tile
// staged once, 3 B tiles; 128x64 tile, BK=64, swizzled LDS) writing Q,K
// [b][h][s][64] and V transposed [b][h][64][s] -> causal flash attention
// (r9 4-wave paired-chain structure; K LDS-staged dbuf; V read DIRECTLY
// from global/L2 -- DS pipe was 68% busy and V needs no staging; setprio
// around MFMA clusters; swapped QK^T -> packed b64 P-stores; fixed-ref-max
// softmax; row-sum via all-ones MFMA).
// ---------------------------------------------------------------------------

typedef unsigned short u16;
typedef unsigned long long u64;
typedef __bf16 bf16x8 __attribute__((ext_vector_type(8)));
typedef float f32x4 __attribute__((ext_vector_type(4)));
typedef u16 u16x8 __attribute__((ext_vector_type(8)));

#define NB 2
#define NS 2048
#define ND 1024
#define NH 16
#define HD 64

__device__ __forceinline__ u16 f2bf(float f) {
    unsigned int u = __float_as_uint(f);
    unsigned int r = u + 0x7fffu + ((u >> 16) & 1u);
    return (u16)(r >> 16);
}

__device__ __forceinline__ f32x4 mfma16(bf16x8 a, bf16x8 b, f32x4 c) {
    return __builtin_amdgcn_mfma_f32_16x16x32_bf16(a, b, c, 0, 0, 0);
}

__device__ __forceinline__ void gl_lds16(const void* g, void* l) {
    __builtin_amdgcn_global_load_lds(
        (const __attribute__((address_space(1))) unsigned int*)g,
        (__attribute__((address_space(3))) unsigned int*)l, 16, 0, 0);
}

// swizzled LDS fragment read from a [rows][128B] tile
__device__ __forceinline__ bf16x8 ldsw(const u16* base, int row, int colb) {
    return *(const bf16x8*)((const char*)base + row * 128 +
                            (colb ^ ((row & 7) << 4)));
}

// --- x (fp32) -> xb (bf16) -------------------------------------------------
__global__ __launch_bounds__(256) void convx_k(const float* __restrict__ x,
                                               u16* __restrict__ xb) {
    int i = (blockIdx.x * 256 + threadIdx.x) * 8;
    const float4* p = (const float4*)(x + i);
    float4 a = p[0], c = p[1];
    u16x8 r;
    r[0] = f2bf(a.x); r[1] = f2bf(a.y); r[2] = f2bf(a.z); r[3] = f2bf(a.w);
    r[4] = f2bf(c.x); r[5] = f2bf(c.y); r[6] = f2bf(c.z); r[7] = f2bf(c.w);
    *(u16x8*)(xb + i) = r;
}

// --- W [k][n] fp32 -> Wt [z][n][k] bf16 ------------------------------------
__global__ __launch_bounds__(256) void convw_k(const float* __restrict__ wq,
                                               const float* __restrict__ wk,
                                               const float* __restrict__ wv,
                                               u16* __restrict__ wt) {
    __shared__ float tile[32][33];
    const int z = blockIdx.z;
    const float* W = (z == 0) ? wq : (z == 1) ? wk : wv;
    const int k0 = blockIdx.x * 32, n0 = blockIdx.y * 32;
    const int tx = threadIdx.x & 31, ty = threadIdx.x >> 5;
#pragma unroll
    for (int rr = 0; rr < 32; rr += 8)
        tile[ty + rr][tx] = W[(size_t)(k0 + ty + rr) * ND + n0 + tx];
    __syncthreads();
    u16* dst = wt + (size_t)z * ND * ND;
#pragma unroll
    for (int rr = 0; rr < 32; rr += 8)
        dst[(size_t)(n0 + ty + rr) * ND + k0 + tx] = f2bf(tile[tx][ty + rr]);
}

// --- z-fused QKV GEMM ------------------------------------------------------
// Grid (32,16): m0 = bx*128, n0 = by*64. 256 threads = 4 waves (2M x 2N),
// wave owns 64x32 per z. BK=64. A staged once + 3 B tiles per K-step.
__global__ __launch_bounds__(256) void qkv_gemm_k(const u16* __restrict__ xb,
                                                  const u16* __restrict__ wt,
                                                  u16* __restrict__ qh,
                                                  u16* __restrict__ kh,
                                                  u16* __restrict__ vt) {
    __shared__ u16 At[128 * 64];     // 16 KiB
    __shared__ u16 Bt[3][64 * 64];   // 3 x 8 KiB
    const int m0 = blockIdx.x * 128;
    const int n0 = blockIdx.y * 64;
    const int t = threadIdx.x;
    const int lane = t & 63;
    const int wv = t >> 6;
    const int wm = (wv >> 1) * 64, wn = (wv & 1) * 32;
    const int fr = lane & 15;
    const int ks = lane >> 4;

    f32x4 acc[3][4][2] = {};

    for (int kt = 0; kt < ND; kt += 64) {
#pragma unroll
        for (int c = 0; c < 4; c++) {
            const int L = c * 4096 + t * 16;
            const int row = L >> 7;
            const int cb = (L & 127) ^ ((row & 7) << 4);
            gl_lds16((const char*)xb + (size_t)(m0 + row) * 2048 + kt * 2 + cb,
                     (char*)At + L);
        }
#pragma unroll
        for (int z = 0; z < 3; z++)
#pragma unroll
            for (int c = 0; c < 2; c++) {
                const int L = c * 4096 + t * 16;
                const int row = L >> 7;  // 0..63
                const int cb = (L & 127) ^ ((row & 7) << 4);
                gl_lds16((const char*)wt + (size_t)z * (ND * ND * 2) +
                             (size_t)(n0 + row) * 2048 + kt * 2 + cb,
                         (char*)&Bt[z][0] + L);
            }
        __syncthreads();

        bf16x8 fa[4][2];
#pragma unroll
        for (int i = 0; i < 4; i++)
#pragma unroll
            for (int c = 0; c < 2; c++)
                fa[i][c] = ldsw(At, wm + i * 16 + fr, c * 64 + ks * 16);

#pragma unroll
        for (int z = 0; z < 3; z++) {
            bf16x8 fb[2][2];
#pragma unroll
            for (int j = 0; j < 2; j++)
#pragma unroll
                for (int c = 0; c < 2; c++)
                    fb[j][c] =
                        ldsw(&Bt[z][0], wn + j * 16 + fr, c * 64 + ks * 16);
            if (z < 2) {
#pragma unroll
                for (int i = 0; i < 4; i++)
#pragma unroll
                    for (int j = 0; j < 2; j++)
#pragma unroll
                        for (int c = 0; c < 2; c++)
                            acc[z][i][j] =
                                mfma16(fa[i][c], fb[j][c], acc[z][i][j]);
            } else {
#pragma unroll
                for (int i = 0; i < 4; i++)
#pragma unroll
                    for (int j = 0; j < 2; j++)
#pragma unroll
                        for (int c = 0; c < 2; c++)
                            acc[z][i][j] =
                                mfma16(fb[j][c], fa[i][c], acc[z][i][j]);
            }
        }
        __syncthreads();
    }

#pragma unroll
    for (int z = 0; z < 2; z++) {
        u16* dst = (z == 0) ? qh : kh;
#pragma unroll
        for (int i = 0; i < 4; i++)
#pragma unroll
            for (int j = 0; j < 2; j++)
#pragma unroll
                for (int r = 0; r < 4; r++) {
                    int mg = m0 + wm + i * 16 + ks * 4 + r;
                    int ng = n0 + wn + j * 16 + fr;
                    int b = mg >> 11, s = mg & 2047;
                    int hh = ng >> 6, dd = ng & 63;
                    dst[(((size_t)b * NH + hh) * NS + s) * HD + dd] =
                        f2bf(acc[z][i][j][r]);
                }
    }
#pragma unroll
    for (int i = 0; i < 4; i++)
#pragma unroll
        for (int j = 0; j < 2; j++)
#pragma unroll
            for (int r = 0; r < 4; r++) {
                int ng = n0 + wn + j * 16 + ks * 4 + r;  // d-dim
                int mg = m0 + wm + i * 16 + fr;          // s-dim
                int b = mg >> 11, s = mg & 2047;
                int hh = ng >> 6, dd = ng & 63;
                vt[(((size_t)b * NH + hh) * HD + dd) * NS + s] =
                    f2bf(acc[2][i][j][r]);
            }
}

// --- causal flash attention ------------------------------------------------
// 512 blocks x 256 threads (4 waves). bh = blk&31 (XCD-affine), p = blk>>5.
// Block handles q-tiles A=31-p (heavy) and B=p (light): uniform 33 KV-iters.
// K tiles staged in LDS (dbuf, swizzled); V read DIRECTLY from global (L2-
// affine, 64B runs, issued before QK so latency hides under QK+softmax).
// Swapped QK^T -> packed b64 P-stores; fixed-ref-max softmax p=exp(s/8-8);
// row-sum via all-ones MFMA. setprio(1) around MFMA clusters (T5).

__device__ __forceinline__ void stage_k(const u16* __restrict__ K, int kv0,
                                        u16* Kl, int t) {
#pragma unroll
    for (int c = 0; c < 2; c++) {
        const int L = c * 4096 + t * 16;
        const int row = L >> 7;
        const int cb = (L & 127) ^ ((row & 7) << 4);
        gl_lds16((const char*)K + (size_t)(kv0 + row) * 128 + cb,
                 (char*)Kl + L);
    }
}

// sc holds S^T fragments; write P[q=fr][kv] as 4 x ds_write_b64
template <bool MASKED>
__device__ __forceinline__ void sm_pxT(const f32x4* sc, u16* pl, int kv0,
                                       int q0, int fr, int ks) {
    const int qg = q0 + fr;
#pragma unroll
    for (int kf = 0; kf < 4; kf++) {
        const int kvb = kv0 + kf * 16 + ks * 4;
        float p[4];
#pragma unroll
        for (int r = 0; r < 4; r++) {
            float s = sc[kf][r];
            if (MASKED && (kvb + r > qg)) s = -3.0e38f;
            p[r] = __expf(fmaf(s, 0.125f, -8.0f));
        }
        u64 w = (u64)f2bf(p[0]) | ((u64)f2bf(p[1]) << 16) |
                ((u64)f2bf(p[2]) << 32) | ((u64)f2bf(p[3]) << 48);
        const int chunk = (2 * kf + (ks >> 1)) ^ (fr & 7);
        *(u64*)((char*)pl + fr * 128 + (chunk << 4) + ((ks & 1) << 3)) = w;
    }
}

__device__ __forceinline__ void pv_g(const bf16x8 (*fv)[2], const u16* pl,
                                     f32x4* o, f32x4& lacc, bf16x8 ones,
                                     int fr, int ks) {
    bf16x8 pa[2];
#pragma unroll
    for (int s2 = 0; s2 < 2; s2++) {
        const int c = (s2 * 4 + ks) ^ (fr & 7);
        pa[s2] = *(const bf16x8*)((const char*)pl + fr * 128 + (c << 4));
    }
    __builtin_amdgcn_s_setprio(1);
    lacc = mfma16(pa[0], ones, lacc);
    lacc = mfma16(pa[1], ones, lacc);
#pragma unroll
    for (int j = 0; j < 4; j++)
#pragma unroll
        for (int s2 = 0; s2 < 2; s2++) o[j] = mfma16(pa[s2], fv[j][s2], o[j]);
    __builtin_amdgcn_s_setprio(0);
}

__global__ __launch_bounds__(256, 2) void attn_k(const u16* __restrict__ qh,
                                                 const u16* __restrict__ kh,
                                                 const u16* __restrict__ vt,
                                                 float* __restrict__ out) {
    const int t = threadIdx.x, lane = t & 63, wv = t >> 6;
    const int fr = lane & 15, ks = lane >> 4;
    const int bh = blockIdx.x & 31;
    const int p = blockIdx.x >> 5;  // 0..15
    const int b = bh >> 4, h = bh & 15;
    const int tileA = 31 - p, tileB = p;
    const int qA = tileA * 64 + wv * 16;
    const int qB = tileB * 64 + wv * 16;
    const int nA = tileA + 1, nB = tileB + 1;
    const u16* Q = qh + (size_t)bh * NS * HD;
    const u16* K = kh + (size_t)bh * NS * HD;
    const u16* V = vt + (size_t)bh * HD * NS;

    __shared__ u16 Kl[2][64 * 64];      // 16 KiB (dbuf)
    __shared__ u16 P[4][2][16 * 64];    // 16 KiB
    u16* plA = &P[wv][0][0];
    u16* plB = &P[wv][1][0];

    bf16x8 fqA[2], fqB[2];
#pragma unroll
    for (int sl = 0; sl < 2; sl++) {
        fqA[sl] = *(const bf16x8*)&Q[(qA + fr) * HD + sl * 32 + ks * 8];
        fqB[sl] = *(const bf16x8*)&Q[(qB + fr) * HD + sl * 32 + ks * 8];
    }

    u16x8 ob;
#pragma unroll
    for (int j = 0; j < 8; j++) ob[j] = 0x3F80;  // bf16 1.0
    const bf16x8 ones = __builtin_bit_cast(bf16x8, ob);

    f32x4 oA[4] = {}, oB[4] = {};
    f32x4 lA = {}, lB = {};

    stage_k(K, 0, &Kl[0][0], t);
    __syncthreads();

    for (int it = 0; it < nA; ++it) {
        const int cur = it & 1;
        const int kv0 = it * 64;
        if (it + 1 < nA) stage_k(K, kv0 + 64, &Kl[cur ^ 1][0], t);

        bf16x8 fk[4][2];
#pragma unroll
        for (int kf = 0; kf < 4; kf++)
#pragma unroll
            for (int sl = 0; sl < 2; sl++)
                fk[kf][sl] = ldsw(&Kl[cur][0], kf * 16 + fr,
                                  sl * 64 + ks * 16);

        // V fragments direct from global (L2); issued before QK so the
        // ~200cy L2 latency hides under QK MFMA + softmax VALU.
        bf16x8 fv[4][2];
#pragma unroll
        for (int j = 0; j < 4; j++)
#pragma unroll
            for (int s2 = 0; s2 < 2; s2++)
                fv[j][s2] = *(const bf16x8*)&V[(j * 16 + fr) * NS + kv0 +
                                               s2 * 32 + ks * 8];

        // swapped QK^T: sc = S^T fragments
        f32x4 scA[4] = {}, scB[4] = {};
        const bool doB = it < nB;
        __builtin_amdgcn_s_setprio(1);
#pragma unroll
        for (int kf = 0; kf < 4; kf++) {
            scA[kf] = mfma16(fk[kf][0], fqA[0], scA[kf]);
            scA[kf] = mfma16(fk[kf][1], fqA[1], scA[kf]);
        }
        if (doB) {
#pragma unroll
            for (int kf = 0; kf < 4; kf++) {
                scB[kf] = mfma16(fk[kf][0], fqB[0], scB[kf]);
                scB[kf] = mfma16(fk[kf][1], fqB[1], scB[kf]);
            }
        }
        __builtin_amdgcn_s_setprio(0);

        if (it == nA - 1)
            sm_pxT<true>(scA, plA, kv0, qA, fr, ks);
        else
            sm_pxT<false>(scA, plA, kv0, qA, fr, ks);
        if (doB) {
            if (it == nB - 1)
                sm_pxT<true>(scB, plB, kv0, qB, fr, ks);
            else
                sm_pxT<false>(scB, plB, kv0, qB, fr, ks);
        }

        pv_g(fv, plA, oA, lA, ones, fr, ks);
        if (doB) pv_g(fv, plB, oB, lB, ones, fr, ks);

        __syncthreads();
    }

    float rlA[4], rlB[4];
#pragma unroll
    for (int r = 0; r < 4; r++) {
        rlA[r] = 1.0f / lA[r];
        rlB[r] = 1.0f / lB[r];
    }
#pragma unroll
    for (int j = 0; j < 4; j++)
#pragma unroll
        for (int r = 0; r < 4; r++) {
            const int qgA = qA + ks * 4 + r;
            const int qgB = qB + ks * 4 + r;
            out[((size_t)b * NS + qgA) * ND + h * HD + j * 16 + fr] =
                oA[j][r] * rlA[r];
            out[((size_t)b * NS + qgB) * ND + h * HD + j * 16 + fr] =
                oB[j][r] * rlB[r];
        }
}

extern "C" void kernel_launch(void* const* d_in, const int* in_sizes, int n_in,
                              void* d_out, int out_size, void* d_ws,
                              size_t ws_size, hipStream_t stream) {
    const float* x = (const float*)d_in[0];
    const float* wq = (const float*)d_in[1];
    const float* wk = (const float*)d_in[2];
    const float* wvp = (const float*)d_in[3];
    float* out = (float*)d_out;

    char* w8 = (char*)d_ws;
    u16* xb = (u16*)(w8);                      // 8 MiB
    u16* wt = (u16*)(w8 + ((size_t)8 << 20));  // 6 MiB
    u16* qh = (u16*)(w8 + ((size_t)14 << 20));
    u16* kh = (u16*)(w8 + ((size_t)22 << 20));
    u16* vt = (u16*)(w8 + ((size_t)30 << 20));

    convx_k<<<(NB * NS * ND) / (256 * 8), 256, 0, stream>>>(x, xb);
    convw_k<<<dim3(ND / 32, ND / 32, 3), 256, 0, stream>>>(wq, wk, wvp, wt);
    qkv_gemm_k<<<dim3((NB * NS) / 128, ND / 64), 256, 0, stream>>>(
        xb, wt, qh, kh, vt);
    attn_k<<<512, 256, 0, stream>>>(qh, kh, vt, out);
}

// Round 12
// 107.527 us; speedup vs baseline: 1.0103x; 1.0103x over previous
//
#include <hip/hip_runtime.h>

// ---------------------------------------------------------------------------
// maskselfattention: B=2, S=2048, D=1024, H=16, hd=64
// convert x,W to bf16 (W transposed) -> ONE fused QKV GEMM (z-fused: A tile
// staged once, 3 B tiles; 128x64 tile, BK=64, swizzled LDS) writing Q,K
// [b][h][s][64] and V transposed [b][h][64][s] -> causal flash attention
// (4-wave paired-chain; K LDS-staged dbuf; V read direct from global/L2 with
// fv ISSUED BEFORE stage_k so PV waits vmcnt(2), not vmcnt(0) -- r11's
// regression was stage-before-fv forcing a full drain; swapped QK^T ->
// packed b64 P-stores; fixed-ref-max softmax; row-sum via all-ones MFMA).
// ---------------------------------------------------------------------------

typedef unsigned short u16;
typedef unsigned long long u64;
typedef __bf16 bf16x8 __attribute__((ext_vector_type(8)));
typedef float f32x4 __attribute__((ext_vector_type(4)));
typedef u16 u16x8 __attribute__((ext_vector_type(8)));

#define NB 2
#define NS 2048
#define ND 1024
#define NH 16
#define HD 64

__device__ __forceinline__ u16 f2bf(float f) {
    unsigned int u = __float_as_uint(f);
    unsigned int r = u + 0x7fffu + ((u >> 16) & 1u);
    return (u16)(r >> 16);
}

__device__ __forceinline__ f32x4 mfma16(bf16x8 a, bf16x8 b, f32x4 c) {
    return __builtin_amdgcn_mfma_f32_16x16x32_bf16(a, b, c, 0, 0, 0);
}

__device__ __forceinline__ void gl_lds16(const void* g, void* l) {
    __builtin_amdgcn_global_load_lds(
        (const __attribute__((address_space(1))) unsigned int*)g,
        (__attribute__((address_space(3))) unsigned int*)l, 16, 0, 0);
}

// swizzled LDS fragment read from a [rows][128B] tile
__device__ __forceinline__ bf16x8 ldsw(const u16* base, int row, int colb) {
    return *(const bf16x8*)((const char*)base + row * 128 +
                            (colb ^ ((row & 7) << 4)));
}

// --- x (fp32) -> xb (bf16) -------------------------------------------------
__global__ __launch_bounds__(256) void convx_k(const float* __restrict__ x,
                                               u16* __restrict__ xb) {
    int i = (blockIdx.x * 256 + threadIdx.x) * 8;
    const float4* p = (const float4*)(x + i);
    float4 a = p[0], c = p[1];
    u16x8 r;
    r[0] = f2bf(a.x); r[1] = f2bf(a.y); r[2] = f2bf(a.z); r[3] = f2bf(a.w);
    r[4] = f2bf(c.x); r[5] = f2bf(c.y); r[6] = f2bf(c.z); r[7] = f2bf(c.w);
    *(u16x8*)(xb + i) = r;
}

// --- W [k][n] fp32 -> Wt [z][n][k] bf16 ------------------------------------
__global__ __launch_bounds__(256) void convw_k(const float* __restrict__ wq,
                                               const float* __restrict__ wk,
                                               const float* __restrict__ wv,
                                               u16* __restrict__ wt) {
    __shared__ float tile[32][33];
    const int z = blockIdx.z;
    const float* W = (z == 0) ? wq : (z == 1) ? wk : wv;
    const int k0 = blockIdx.x * 32, n0 = blockIdx.y * 32;
    const int tx = threadIdx.x & 31, ty = threadIdx.x >> 5;
#pragma unroll
    for (int rr = 0; rr < 32; rr += 8)
        tile[ty + rr][tx] = W[(size_t)(k0 + ty + rr) * ND + n0 + tx];
    __syncthreads();
    u16* dst = wt + (size_t)z * ND * ND;
#pragma unroll
    for (int rr = 0; rr < 32; rr += 8)
        dst[(size_t)(n0 + ty + rr) * ND + k0 + tx] = f2bf(tile[tx][ty + rr]);
}

// --- z-fused QKV GEMM ------------------------------------------------------
// Grid (32,16): m0 = bx*128, n0 = by*64. 256 threads = 4 waves (2M x 2N),
// wave owns 64x32 per z. BK=64. A staged once + 3 B tiles per K-step.
__global__ __launch_bounds__(256) void qkv_gemm_k(const u16* __restrict__ xb,
                                                  const u16* __restrict__ wt,
                                                  u16* __restrict__ qh,
                                                  u16* __restrict__ kh,
                                                  u16* __restrict__ vt) {
    __shared__ u16 At[128 * 64];     // 16 KiB
    __shared__ u16 Bt[3][64 * 64];   // 3 x 8 KiB
    const int m0 = blockIdx.x * 128;
    const int n0 = blockIdx.y * 64;
    const int t = threadIdx.x;
    const int lane = t & 63;
    const int wv = t >> 6;
    const int wm = (wv >> 1) * 64, wn = (wv & 1) * 32;
    const int fr = lane & 15;
    const int ks = lane >> 4;

    f32x4 acc[3][4][2] = {};

    for (int kt = 0; kt < ND; kt += 64) {
#pragma unroll
        for (int c = 0; c < 4; c++) {
            const int L = c * 4096 + t * 16;
            const int row = L >> 7;
            const int cb = (L & 127) ^ ((row & 7) << 4);
            gl_lds16((const char*)xb + (size_t)(m0 + row) * 2048 + kt * 2 + cb,
                     (char*)At + L);
        }
#pragma unroll
        for (int z = 0; z < 3; z++)
#pragma unroll
            for (int c = 0; c < 2; c++) {
                const int L = c * 4096 + t * 16;
                const int row = L >> 7;  // 0..63
                const int cb = (L & 127) ^ ((row & 7) << 4);
                gl_lds16((const char*)wt + (size_t)z * (ND * ND * 2) +
                             (size_t)(n0 + row) * 2048 + kt * 2 + cb,
                         (char*)&Bt[z][0] + L);
            }
        __syncthreads();

        bf16x8 fa[4][2];
#pragma unroll
        for (int i = 0; i < 4; i++)
#pragma unroll
            for (int c = 0; c < 2; c++)
                fa[i][c] = ldsw(At, wm + i * 16 + fr, c * 64 + ks * 16);

#pragma unroll
        for (int z = 0; z < 3; z++) {
            bf16x8 fb[2][2];
#pragma unroll
            for (int j = 0; j < 2; j++)
#pragma unroll
                for (int c = 0; c < 2; c++)
                    fb[j][c] =
                        ldsw(&Bt[z][0], wn + j * 16 + fr, c * 64 + ks * 16);
            if (z < 2) {
#pragma unroll
                for (int i = 0; i < 4; i++)
#pragma unroll
                    for (int j = 0; j < 2; j++)
#pragma unroll
                        for (int c = 0; c < 2; c++)
                            acc[z][i][j] =
                                mfma16(fa[i][c], fb[j][c], acc[z][i][j]);
            } else {
#pragma unroll
                for (int i = 0; i < 4; i++)
#pragma unroll
                    for (int j = 0; j < 2; j++)
#pragma unroll
                        for (int c = 0; c < 2; c++)
                            acc[z][i][j] =
                                mfma16(fb[j][c], fa[i][c], acc[z][i][j]);
            }
        }
        __syncthreads();
    }

#pragma unroll
    for (int z = 0; z < 2; z++) {
        u16* dst = (z == 0) ? qh : kh;
#pragma unroll
        for (int i = 0; i < 4; i++)
#pragma unroll
            for (int j = 0; j < 2; j++)
#pragma unroll
                for (int r = 0; r < 4; r++) {
                    int mg = m0 + wm + i * 16 + ks * 4 + r;
                    int ng = n0 + wn + j * 16 + fr;
                    int b = mg >> 11, s = mg & 2047;
                    int hh = ng >> 6, dd = ng & 63;
                    dst[(((size_t)b * NH + hh) * NS + s) * HD + dd] =
                        f2bf(acc[z][i][j][r]);
                }
    }
#pragma unroll
    for (int i = 0; i < 4; i++)
#pragma unroll
        for (int j = 0; j < 2; j++)
#pragma unroll
            for (int r = 0; r < 4; r++) {
                int ng = n0 + wn + j * 16 + ks * 4 + r;  // d-dim
                int mg = m0 + wm + i * 16 + fr;          // s-dim
                int b = mg >> 11, s = mg & 2047;
                int hh = ng >> 6, dd = ng & 63;
                vt[(((size_t)b * NH + hh) * HD + dd) * NS + s] =
                    f2bf(acc[2][i][j][r]);
            }
}

// --- causal flash attention ------------------------------------------------
// 512 blocks x 256 threads (4 waves). bh = blk&31 (XCD-affine), p = blk>>5.
// Block handles q-tiles A=31-p (heavy) and B=p (light): uniform 33 KV-iters.
// K tiles staged in LDS (dbuf, swizzled). V read DIRECTLY from global:
// fv loads issued FIRST each iter, stage_k second -> auto-waitcnt before PV
// is vmcnt(2) (K prefetch stays in flight; r11 had the order inverted which
// forced vmcnt(0) and serialized the pipeline). Swapped QK^T -> packed b64
// P-stores; fixed-ref-max softmax p=exp(s/8-8); row-sum via all-ones MFMA.

__device__ __forceinline__ void stage_k(const u16* __restrict__ K, int kv0,
                                        u16* Kl, int t) {
#pragma unroll
    for (int c = 0; c < 2; c++) {
        const int L = c * 4096 + t * 16;
        const int row = L >> 7;
        const int cb = (L & 127) ^ ((row & 7) << 4);
        gl_lds16((const char*)K + (size_t)(kv0 + row) * 128 + cb,
                 (char*)Kl + L);
    }
}

// sc holds S^T fragments; write P[q=fr][kv] as 4 x ds_write_b64
template <bool MASKED>
__device__ __forceinline__ void sm_pxT(const f32x4* sc, u16* pl, int kv0,
                                       int q0, int fr, int ks) {
    const int qg = q0 + fr;
#pragma unroll
    for (int kf = 0; kf < 4; kf++) {
        const int kvb = kv0 + kf * 16 + ks * 4;
        float p[4];
#pragma unroll
        for (int r = 0; r < 4; r++) {
            float s = sc[kf][r];
            if (MASKED && (kvb + r > qg)) s = -3.0e38f;
            p[r] = __expf(fmaf(s, 0.125f, -8.0f));
        }
        u64 w = (u64)f2bf(p[0]) | ((u64)f2bf(p[1]) << 16) |
                ((u64)f2bf(p[2]) << 32) | ((u64)f2bf(p[3]) << 48);
        const int chunk = (2 * kf + (ks >> 1)) ^ (fr & 7);
        *(u64*)((char*)pl + fr * 128 + (chunk << 4) + ((ks & 1) << 3)) = w;
    }
}

__device__ __forceinline__ void pv_g(const bf16x8 (*fv)[2], const u16* pl,
                                     f32x4* o, f32x4& lacc, bf16x8 ones,
                                     int fr, int ks) {
    bf16x8 pa[2];
#pragma unroll
    for (int s2 = 0; s2 < 2; s2++) {
        const int c = (s2 * 4 + ks) ^ (fr & 7);
        pa[s2] = *(const bf16x8*)((const char*)pl + fr * 128 + (c << 4));
    }
    __builtin_amdgcn_s_setprio(1);
    lacc = mfma16(pa[0], ones, lacc);
    lacc = mfma16(pa[1], ones, lacc);
#pragma unroll
    for (int j = 0; j < 4; j++)
#pragma unroll
        for (int s2 = 0; s2 < 2; s2++) o[j] = mfma16(pa[s2], fv[j][s2], o[j]);
    __builtin_amdgcn_s_setprio(0);
}

__global__ __launch_bounds__(256, 2) void attn_k(const u16* __restrict__ qh,
                                                 const u16* __restrict__ kh,
                                                 const u16* __restrict__ vt,
                                                 float* __restrict__ out) {
    const int t = threadIdx.x, lane = t & 63, wv = t >> 6;
    const int fr = lane & 15, ks = lane >> 4;
    const int bh = blockIdx.x & 31;
    const int p = blockIdx.x >> 5;  // 0..15
    const int b = bh >> 4, h = bh & 15;
    const int tileA = 31 - p, tileB = p;
    const int qA = tileA * 64 + wv * 16;
    const int qB = tileB * 64 + wv * 16;
    const int nA = tileA + 1, nB = tileB + 1;
    const u16* Q = qh + (size_t)bh * NS * HD;
    const u16* K = kh + (size_t)bh * NS * HD;
    const u16* V = vt + (size_t)bh * HD * NS;

    __shared__ u16 Kl[2][64 * 64];      // 16 KiB (dbuf)
    __shared__ u16 P[4][2][16 * 64];    // 16 KiB
    u16* plA = &P[wv][0][0];
    u16* plB = &P[wv][1][0];

    bf16x8 fqA[2], fqB[2];
#pragma unroll
    for (int sl = 0; sl < 2; sl++) {
        fqA[sl] = *(const bf16x8*)&Q[(qA + fr) * HD + sl * 32 + ks * 8];
        fqB[sl] = *(const bf16x8*)&Q[(qB + fr) * HD + sl * 32 + ks * 8];
    }

    u16x8 ob;
#pragma unroll
    for (int j = 0; j < 8; j++) ob[j] = 0x3F80;  // bf16 1.0
    const bf16x8 ones = __builtin_bit_cast(bf16x8, ob);

    f32x4 oA[4] = {}, oB[4] = {};
    f32x4 lA = {}, lB = {};

    stage_k(K, 0, &Kl[0][0], t);
    __syncthreads();

    for (int it = 0; it < nA; ++it) {
        const int cur = it & 1;
        const int kv0 = it * 64;

        // 1) V fragments direct from global -- issued FIRST so the wait
        //    before PV is vmcnt(2) (stage ops still in flight), not 0.
        bf16x8 fv[4][2];
#pragma unroll
        for (int j = 0; j < 4; j++)
#pragma unroll
            for (int s2 = 0; s2 < 2; s2++)
                fv[j][s2] = *(const bf16x8*)&V[(j * 16 + fr) * NS + kv0 +
                                               s2 * 32 + ks * 8];
        __builtin_amdgcn_sched_barrier(0);

        // 2) stage next K tile (issue-after-fv is load-bearing)
        if (it + 1 < nA) stage_k(K, kv0 + 64, &Kl[cur ^ 1][0], t);
        __builtin_amdgcn_sched_barrier(0);

        // 3) K fragments from LDS
        bf16x8 fk[4][2];
#pragma unroll
        for (int kf = 0; kf < 4; kf++)
#pragma unroll
            for (int sl = 0; sl < 2; sl++)
                fk[kf][sl] = ldsw(&Kl[cur][0], kf * 16 + fr,
                                  sl * 64 + ks * 16);

        // 4) swapped QK^T: sc = S^T fragments
        f32x4 scA[4] = {}, scB[4] = {};
        const bool doB = it < nB;
        __builtin_amdgcn_s_setprio(1);
#pragma unroll
        for (int kf = 0; kf < 4; kf++) {
            scA[kf] = mfma16(fk[kf][0], fqA[0], scA[kf]);
            scA[kf] = mfma16(fk[kf][1], fqA[1], scA[kf]);
        }
        if (doB) {
#pragma unroll
            for (int kf = 0; kf < 4; kf++) {
                scB[kf] = mfma16(fk[kf][0], fqB[0], scB[kf]);
                scB[kf] = mfma16(fk[kf][1], fqB[1], scB[kf]);
            }
        }
        __builtin_amdgcn_s_setprio(0);

        // 5) softmax + packed P-store
        if (it == nA - 1)
            sm_pxT<true>(scA, plA, kv0, qA, fr, ks);
        else
            sm_pxT<false>(scA, plA, kv0, qA, fr, ks);
        if (doB) {
            if (it == nB - 1)
                sm_pxT<true>(scB, plB, kv0, qB, fr, ks);
            else
                sm_pxT<false>(scB, plB, kv0, qB, fr, ks);
        }

        // 6) PV (waits vmcnt(2) for fv; lgkm for P)
        pv_g(fv, plA, oA, lA, ones, fr, ks);
        if (doB) pv_g(fv, plB, oB, lB, ones, fr, ks);

        __syncthreads();
    }

    float rlA[4], rlB[4];
#pragma unroll
    for (int r = 0; r < 4; r++) {
        rlA[r] = 1.0f / lA[r];
        rlB[r] = 1.0f / lB[r];
    }
#pragma unroll
    for (int j = 0; j < 4; j++)
#pragma unroll
        for (int r = 0; r < 4; r++) {
            const int qgA = qA + ks * 4 + r;
            const int qgB = qB + ks * 4 + r;
            out[((size_t)b * NS + qgA) * ND + h * HD + j * 16 + fr] =
                oA[j][r] * rlA[r];
            out[((size_t)b * NS + qgB) * ND + h * HD + j * 16 + fr] =
                oB[j][r] * rlB[r];
        }
}

extern "C" void kernel_launch(void* const* d_in, const int* in_sizes, int n_in,
                              void* d_out, int out_size, void* d_ws,
                              size_t ws_size, hipStream_t stream) {
    const float* x = (const float*)d_in[0];
    const float* wq = (const float*)d_in[1];
    const float* wk = (const float*)d_in[2];
    const float* wvp = (const float*)d_in[3];
    float* out = (float*)d_out;

    char* w8 = (char*)d_ws;
    u16* xb = (u16*)(w8);                      // 8 MiB
    u16* wt = (u16*)(w8 + ((size_t)8 << 20));  // 6 MiB
    u16* qh = (u16*)(w8 + ((size_t)14 << 20));
    u16* kh = (u16*)(w8 + ((size_t)22 << 20));
    u16* vt = (u16*)(w8 + ((size_t)30 << 20));

    convx_k<<<(NB * NS * ND) / (256 * 8), 256, 0, stream>>>(x, xb);
    convw_k<<<dim3(ND / 32, ND / 32, 3), 256, 0, stream>>>(wq, wk, wvp, wt);
    qkv_gemm_k<<<dim3((NB * NS) / 128, ND / 64), 256, 0, stream>>>(
        xb, wt, qh, kh, vt);
    attn_k<<<512, 256, 0, stream>>>(qh, kh, vt, out);
}

// Round 13
// 107.393 us; speedup vs baseline: 1.0116x; 1.0013x over previous
//
#include <hip/hip_runtime.h>

// ---------------------------------------------------------------------------
// maskselfattention: B=2, S=2048, D=1024, H=16, hd=64
// convert x,W to bf16 (W transposed) -> ONE fused QKV GEMM (z-fused: A tile
// staged once, 3 B tiles; 128x64 tile, BK=64, swizzled LDS) writing Q,K
// [b][h][s][64] and V transposed [b][h][64][s] -> causal flash attention:
// 512 blocks x 128 thr (2 waves); block owns pair (A=31-p heavy, B=p light);
// wave owns 32q of A + 32q of B = 4 chains sharing one fk/fv LDS read set
// (DS per q -32% vs 2-chain r9 -- DS pipe was the measured limiter).
// K,V LDS-staged dbuf swizzled; swapped QK^T -> packed b64 P-stores into
// 2 alternating per-wave P buffers; exp2-folded fixed-ref-max softmax;
// row-sum via all-ones MFMA.
// ---------------------------------------------------------------------------

typedef unsigned short u16;
typedef unsigned long long u64;
typedef __bf16 bf16x8 __attribute__((ext_vector_type(8)));
typedef float f32x4 __attribute__((ext_vector_type(4)));
typedef u16 u16x8 __attribute__((ext_vector_type(8)));

#define NB 2
#define NS 2048
#define ND 1024
#define NH 16
#define HD 64

__device__ __forceinline__ u16 f2bf(float f) {
    unsigned int u = __float_as_uint(f);
    unsigned int r = u + 0x7fffu + ((u >> 16) & 1u);
    return (u16)(r >> 16);
}

__device__ __forceinline__ f32x4 mfma16(bf16x8 a, bf16x8 b, f32x4 c) {
    return __builtin_amdgcn_mfma_f32_16x16x32_bf16(a, b, c, 0, 0, 0);
}

__device__ __forceinline__ void gl_lds16(const void* g, void* l) {
    __builtin_amdgcn_global_load_lds(
        (const __attribute__((address_space(1))) unsigned int*)g,
        (__attribute__((address_space(3))) unsigned int*)l, 16, 0, 0);
}

// swizzled LDS fragment read from a [rows][128B] tile
__device__ __forceinline__ bf16x8 ldsw(const u16* base, int row, int colb) {
    return *(const bf16x8*)((const char*)base + row * 128 +
                            (colb ^ ((row & 7) << 4)));
}

// --- x (fp32) -> xb (bf16) -------------------------------------------------
__global__ __launch_bounds__(256) void convx_k(const float* __restrict__ x,
                                               u16* __restrict__ xb) {
    int i = (blockIdx.x * 256 + threadIdx.x) * 8;
    const float4* p = (const float4*)(x + i);
    float4 a = p[0], c = p[1];
    u16x8 r;
    r[0] = f2bf(a.x); r[1] = f2bf(a.y); r[2] = f2bf(a.z); r[3] = f2bf(a.w);
    r[4] = f2bf(c.x); r[5] = f2bf(c.y); r[6] = f2bf(c.z); r[7] = f2bf(c.w);
    *(u16x8*)(xb + i) = r;
}

// --- W [k][n] fp32 -> Wt [z][n][k] bf16 ------------------------------------
__global__ __launch_bounds__(256) void convw_k(const float* __restrict__ wq,
                                               const float* __restrict__ wk,
                                               const float* __restrict__ wv,
                                               u16* __restrict__ wt) {
    __shared__ float tile[32][33];
    const int z = blockIdx.z;
    const float* W = (z == 0) ? wq : (z == 1) ? wk : wv;
    const int k0 = blockIdx.x * 32, n0 = blockIdx.y * 32;
    const int tx = threadIdx.x & 31, ty = threadIdx.x >> 5;
#pragma unroll
    for (int rr = 0; rr < 32; rr += 8)
        tile[ty + rr][tx] = W[(size_t)(k0 + ty + rr) * ND + n0 + tx];
    __syncthreads();
    u16* dst = wt + (size_t)z * ND * ND;
#pragma unroll
    for (int rr = 0; rr < 32; rr += 8)
        dst[(size_t)(n0 + ty + rr) * ND + k0 + tx] = f2bf(tile[tx][ty + rr]);
}

// --- z-fused QKV GEMM ------------------------------------------------------
// Grid (32,16): m0 = bx*128, n0 = by*64. 256 threads = 4 waves (2M x 2N),
// wave owns 64x32 per z. BK=64. A staged once + 3 B tiles per K-step.
__global__ __launch_bounds__(256) void qkv_gemm_k(const u16* __restrict__ xb,
                                                  const u16* __restrict__ wt,
                                                  u16* __restrict__ qh,
                                                  u16* __restrict__ kh,
                                                  u16* __restrict__ vt) {
    __shared__ u16 At[128 * 64];     // 16 KiB
    __shared__ u16 Bt[3][64 * 64];   // 3 x 8 KiB
    const int m0 = blockIdx.x * 128;
    const int n0 = blockIdx.y * 64;
    const int t = threadIdx.x;
    const int lane = t & 63;
    const int wv = t >> 6;
    const int wm = (wv >> 1) * 64, wn = (wv & 1) * 32;
    const int fr = lane & 15;
    const int ks = lane >> 4;

    f32x4 acc[3][4][2] = {};

    for (int kt = 0; kt < ND; kt += 64) {
#pragma unroll
        for (int c = 0; c < 4; c++) {
            const int L = c * 4096 + t * 16;
            const int row = L >> 7;
            const int cb = (L & 127) ^ ((row & 7) << 4);
            gl_lds16((const char*)xb + (size_t)(m0 + row) * 2048 + kt * 2 + cb,
                     (char*)At + L);
        }
#pragma unroll
        for (int z = 0; z < 3; z++)
#pragma unroll
            for (int c = 0; c < 2; c++) {
                const int L = c * 4096 + t * 16;
                const int row = L >> 7;  // 0..63
                const int cb = (L & 127) ^ ((row & 7) << 4);
                gl_lds16((const char*)wt + (size_t)z * (ND * ND * 2) +
                             (size_t)(n0 + row) * 2048 + kt * 2 + cb,
                         (char*)&Bt[z][0] + L);
            }
        __syncthreads();

        bf16x8 fa[4][2];
#pragma unroll
        for (int i = 0; i < 4; i++)
#pragma unroll
            for (int c = 0; c < 2; c++)
                fa[i][c] = ldsw(At, wm + i * 16 + fr, c * 64 + ks * 16);

#pragma unroll
        for (int z = 0; z < 3; z++) {
            bf16x8 fb[2][2];
#pragma unroll
            for (int j = 0; j < 2; j++)
#pragma unroll
                for (int c = 0; c < 2; c++)
                    fb[j][c] =
                        ldsw(&Bt[z][0], wn + j * 16 + fr, c * 64 + ks * 16);
            if (z < 2) {
#pragma unroll
                for (int i = 0; i < 4; i++)
#pragma unroll
                    for (int j = 0; j < 2; j++)
#pragma unroll
                        for (int c = 0; c < 2; c++)
                            acc[z][i][j] =
                                mfma16(fa[i][c], fb[j][c], acc[z][i][j]);
            } else {
#pragma unroll
                for (int i = 0; i < 4; i++)
#pragma unroll
                    for (int j = 0; j < 2; j++)
#pragma unroll
                        for (int c = 0; c < 2; c++)
                            acc[z][i][j] =
                                mfma16(fb[j][c], fa[i][c], acc[z][i][j]);
            }
        }
        __syncthreads();
    }

#pragma unroll
    for (int z = 0; z < 2; z++) {
        u16* dst = (z == 0) ? qh : kh;
#pragma unroll
        for (int i = 0; i < 4; i++)
#pragma unroll
            for (int j = 0; j < 2; j++)
#pragma unroll
                for (int r = 0; r < 4; r++) {
                    int mg = m0 + wm + i * 16 + ks * 4 + r;
                    int ng = n0 + wn + j * 16 + fr;
                    int b = mg >> 11, s = mg & 2047;
                    int hh = ng >> 6, dd = ng & 63;
                    dst[(((size_t)b * NH + hh) * NS + s) * HD + dd] =
                        f2bf(acc[z][i][j][r]);
                }
    }
#pragma unroll
    for (int i = 0; i < 4; i++)
#pragma unroll
        for (int j = 0; j < 2; j++)
#pragma unroll
            for (int r = 0; r < 4; r++) {
                int ng = n0 + wn + j * 16 + ks * 4 + r;  // d-dim
                int mg = m0 + wm + i * 16 + fr;          // s-dim
                int b = mg >> 11, s = mg & 2047;
                int hh = ng >> 6, dd = ng & 63;
                vt[(((size_t)b * NH + hh) * HD + dd) * NS + s] =
                    f2bf(acc[2][i][j][r]);
            }
}

// --- causal flash attention ------------------------------------------------
// 512 blocks x 128 threads (2 waves). bh = blk&31 (XCD-affine), p = blk>>5.
// Block owns pair (A=31-p, B=p); wave wv owns rows [32wv, 32wv+32) of BOTH
// tiles = 4 chains {A0,A1,B0,B1}. One fk/fv read set feeds all 4 chains.
// K,V 64-row tiles staged via global_load_lds (dbuf, swizzled). Swapped QK^T
// -> packed b64 P-stores into P[wv][c&1] (alternating buffers; per-wave DS
// ordering makes the reuse safe). p = exp2(fma(s, 0.125*log2e, -8*log2e)).

__device__ __forceinline__ void stage_kv(const u16* __restrict__ K,
                                         const u16* __restrict__ V, int kv0,
                                         u16* Kl, u16* Vl, int t) {
#pragma unroll
    for (int c = 0; c < 4; c++) {
        const int L = c * 2048 + t * 16;
        const int row = L >> 7;
        const int cb = (L & 127) ^ ((row & 7) << 4);
        gl_lds16((const char*)K + (size_t)(kv0 + row) * 128 + cb,
                 (char*)Kl + L);
        gl_lds16((const char*)V + (size_t)row * (NS * 2) + kv0 * 2 + cb,
                 (char*)Vl + L);
    }
}

// sc holds S^T fragments; write P[q=fr][kv] as 4 x ds_write_b64
template <bool MASKED>
__device__ __forceinline__ void sm_pxT(const f32x4* sc, u16* pl, int kv0,
                                       int q0, int fr, int ks) {
    const int qg = q0 + fr;
#pragma unroll
    for (int kf = 0; kf < 4; kf++) {
        const int kvb = kv0 + kf * 16 + ks * 4;
        float p[4];
#pragma unroll
        for (int r = 0; r < 4; r++) {
            float s = sc[kf][r];
            if (MASKED && (kvb + r > qg)) s = -3.0e38f;
            // exp(s/8 - 8) == exp2(s*0.125*log2e - 8*log2e)
            p[r] = exp2f(fmaf(s, 0.18033688f, -11.5415603f));
        }
        u64 w = (u64)f2bf(p[0]) | ((u64)f2bf(p[1]) << 16) |
                ((u64)f2bf(p[2]) << 32) | ((u64)f2bf(p[3]) << 48);
        const int chunk = (2 * kf + (ks >> 1)) ^ (fr & 7);
        *(u64*)((char*)pl + fr * 128 + (chunk << 4) + ((ks & 1) << 3)) = w;
    }
}

__global__ __launch_bounds__(128) void attn_k(const u16* __restrict__ qh,
                                              const u16* __restrict__ kh,
                                              const u16* __restrict__ vt,
                                              float* __restrict__ out) {
    const int t = threadIdx.x, lane = t & 63, wv = t >> 6;  // wv in {0,1}
    const int fr = lane & 15, ks = lane >> 4;
    const int bh = blockIdx.x & 31;
    const int p = blockIdx.x >> 5;  // 0..15
    const int b = bh >> 4, h = bh & 15;
    const int tileA = 31 - p, tileB = p;
    const int nA = tileA + 1, nB = tileB + 1;
    int q0c[4];
    q0c[0] = tileA * 64 + wv * 32;
    q0c[1] = q0c[0] + 16;
    q0c[2] = tileB * 64 + wv * 32;
    q0c[3] = q0c[2] + 16;
    const u16* Q = qh + (size_t)bh * NS * HD;
    const u16* K = kh + (size_t)bh * NS * HD;
    const u16* V = vt + (size_t)bh * HD * NS;

    __shared__ u16 Kl[2][64 * 64];    // 32 KiB dbuf
    __shared__ u16 Vl[2][64 * 64];    // 32 KiB dbuf
    __shared__ u16 P[2][2][16 * 64];  // per-wave 2 alternating buffers, 8 KiB

    bf16x8 fq[4][2];
#pragma unroll
    for (int c = 0; c < 4; c++)
#pragma unroll
        for (int sl = 0; sl < 2; sl++)
            fq[c][sl] =
                *(const bf16x8*)&Q[(q0c[c] + fr) * HD + sl * 32 + ks * 8];

    u16x8 ob;
#pragma unroll
    for (int j = 0; j < 8; j++) ob[j] = 0x3F80;  // bf16 1.0
    const bf16x8 ones = __builtin_bit_cast(bf16x8, ob);

    f32x4 o[4][4] = {};
    f32x4 l[4] = {};

    stage_kv(K, V, 0, &Kl[0][0], &Vl[0][0], t);
    __syncthreads();

    for (int it = 0; it < nA; ++it) {
        const int cur = it & 1;
        const int kv0 = it * 64;
        if (it + 1 < nA)
            stage_kv(K, V, kv0 + 64, &Kl[cur ^ 1][0], &Vl[cur ^ 1][0], t);

        bf16x8 fk[4][2], fv[4][2];
#pragma unroll
        for (int i = 0; i < 4; i++)
#pragma unroll
            for (int sl = 0; sl < 2; sl++) {
                fk[i][sl] = ldsw(&Kl[cur][0], i * 16 + fr, sl * 64 + ks * 16);
                fv[i][sl] = ldsw(&Vl[cur][0], i * 16 + fr, sl * 64 + ks * 16);
            }

        const bool lastA = (it == nA - 1);
        const bool lastB = (it == nB - 1);
        const bool doB = it < nB;

#pragma unroll
        for (int c = 0; c < 4; c++) {
            if (c >= 2 && !doB) continue;
            // swapped QK^T: sc[kf] = S^T fragment (kv rows, q cols)
            f32x4 sc[4] = {};
#pragma unroll
            for (int kf = 0; kf < 4; kf++) {
                sc[kf] = mfma16(fk[kf][0], fq[c][0], sc[kf]);
                sc[kf] = mfma16(fk[kf][1], fq[c][1], sc[kf]);
            }
            u16* pl = &P[wv][c & 1][0];
            const bool lastm = (c < 2) ? lastA : lastB;
            if (lastm)
                sm_pxT<true>(sc, pl, kv0, q0c[c], fr, ks);
            else
                sm_pxT<false>(sc, pl, kv0, q0c[c], fr, ks);

            bf16x8 pa[2];
#pragma unroll
            for (int s2 = 0; s2 < 2; s2++) {
                const int ch = (s2 * 4 + ks) ^ (fr & 7);
                pa[s2] =
                    *(const bf16x8*)((const char*)pl + fr * 128 + (ch << 4));
            }
            l[c] = mfma16(pa[0], ones, l[c]);
            l[c] = mfma16(pa[1], ones, l[c]);
#pragma unroll
            for (int j = 0; j < 4; j++)
#pragma unroll
                for (int s2 = 0; s2 < 2; s2++)
                    o[c][j] = mfma16(pa[s2], fv[j][s2], o[c][j]);
        }

        __syncthreads();
    }

#pragma unroll
    for (int c = 0; c < 4; c++) {
        float rl[4];
#pragma unroll
        for (int r = 0; r < 4; r++) rl[r] = 1.0f / l[c][r];
#pragma unroll
        for (int j = 0; j < 4; j++)
#pragma unroll
            for (int r = 0; r < 4; r++) {
                const int qg = q0c[c] + ks * 4 + r;
                out[((size_t)b * NS + qg) * ND + h * HD + j * 16 + fr] =
                    o[c][j][r] * rl[r];
            }
    }
}

extern "C" void kernel_launch(void* const* d_in, const int* in_sizes, int n_in,
                              void* d_out, int out_size, void* d_ws,
                              size_t ws_size, hipStream_t stream) {
    const float* x = (const float*)d_in[0];
    const float* wq = (const float*)d_in[1];
    const float* wk = (const float*)d_in[2];
    const float* wvp = (const float*)d_in[3];
    float* out = (float*)d_out;

    char* w8 = (char*)d_ws;
    u16* xb = (u16*)(w8);                      // 8 MiB
    u16* wt = (u16*)(w8 + ((size_t)8 << 20));  // 6 MiB
    u16* qh = (u16*)(w8 + ((size_t)14 << 20));
    u16* kh = (u16*)(w8 + ((size_t)22 << 20));
    u16* vt = (u16*)(w8 + ((size_t)30 << 20));

    convx_k<<<(NB * NS * ND) / (256 * 8), 256, 0, stream>>>(x, xb);
    convw_k<<<dim3(ND / 32, ND / 32, 3), 256, 0, stream>>>(wq, wk, wvp, wt);
    qkv_gemm_k<<<dim3((NB * NS) / 128, ND / 64), 256, 0, stream>>>(
        xb, wt, qh, kh, vt);
    attn_k<<<512, 128, 0, stream>>>(qh, kh, vt, out);
}

// Round 14
// 81.668 us; speedup vs baseline: 1.3302x; 1.3150x over previous
//
#include <hip/hip_runtime.h>

// ---------------------------------------------------------------------------
// maskselfattention: B=2, S=2048, D=1024, H=16, hd=64
// convert x,W to bf16 (W transposed) -> ONE fused QKV GEMM (z-fused: A tile
// staged once, 3 B tiles; 128x64 tile, BK=64, swizzled LDS) writing Q,K
// [b][h][s][64] and V^T with kv-PERMUTED columns (pi-layout, see below)
// -> causal flash attention (r9 4-wave paired-chain; K,V LDS-staged dbuf;
// P kept ENTIRELY IN REGISTERS: swapped QK^T output + kv-permutation pi
// chosen so each lane's sc registers ARE its PV A-fragment after exp+cvt.
// PV correctness: sum_kv P[q][kv] V[kv][d] is invariant under permuting kv
// in BOTH P-k and V-rows; GEMM epilogue stores V^T row w at column
// pi^-1(w) within each 64-block, so attn V reads stay linear b128.)
// ---------------------------------------------------------------------------

typedef unsigned short u16;
typedef unsigned long long u64;
typedef __bf16 bf16x8 __attribute__((ext_vector_type(8)));
typedef float f32x4 __attribute__((ext_vector_type(4)));
typedef u16 u16x8 __attribute__((ext_vector_type(8)));

#define NB 2
#define NS 2048
#define ND 1024
#define NH 16
#define HD 64

__device__ __forceinline__ u16 f2bf(float f) {
    unsigned int u = __float_as_uint(f);
    unsigned int r = u + 0x7fffu + ((u >> 16) & 1u);
    return (u16)(r >> 16);
}

__device__ __forceinline__ f32x4 mfma16(bf16x8 a, bf16x8 b, f32x4 c) {
    return __builtin_amdgcn_mfma_f32_16x16x32_bf16(a, b, c, 0, 0, 0);
}

__device__ __forceinline__ void gl_lds16(const void* g, void* l) {
    __builtin_amdgcn_global_load_lds(
        (const __attribute__((address_space(1))) unsigned int*)g,
        (__attribute__((address_space(3))) unsigned int*)l, 16, 0, 0);
}

// swizzled LDS fragment read from a [rows][128B] tile
__device__ __forceinline__ bf16x8 ldsw(const u16* base, int row, int colb) {
    return *(const bf16x8*)((const char*)base + row * 128 +
                            (colb ^ ((row & 7) << 4)));
}

// --- x (fp32) -> xb (bf16) -------------------------------------------------
__global__ __launch_bounds__(256) void convx_k(const float* __restrict__ x,
                                               u16* __restrict__ xb) {
    int i = (blockIdx.x * 256 + threadIdx.x) * 8;
    const float4* p = (const float4*)(x + i);
    float4 a = p[0], c = p[1];
    u16x8 r;
    r[0] = f2bf(a.x); r[1] = f2bf(a.y); r[2] = f2bf(a.z); r[3] = f2bf(a.w);
    r[4] = f2bf(c.x); r[5] = f2bf(c.y); r[6] = f2bf(c.z); r[7] = f2bf(c.w);
    *(u16x8*)(xb + i) = r;
}

// --- W [k][n] fp32 -> Wt [z][n][k] bf16 ------------------------------------
__global__ __launch_bounds__(256) void convw_k(const float* __restrict__ wq,
                                               const float* __restrict__ wk,
                                               const float* __restrict__ wv,
                                               u16* __restrict__ wt) {
    __shared__ float tile[32][33];
    const int z = blockIdx.z;
    const float* W = (z == 0) ? wq : (z == 1) ? wk : wv;
    const int k0 = blockIdx.x * 32, n0 = blockIdx.y * 32;
    const int tx = threadIdx.x & 31, ty = threadIdx.x >> 5;
#pragma unroll
    for (int rr = 0; rr < 32; rr += 8)
        tile[ty + rr][tx] = W[(size_t)(k0 + ty + rr) * ND + n0 + tx];
    __syncthreads();
    u16* dst = wt + (size_t)z * ND * ND;
#pragma unroll
    for (int rr = 0; rr < 32; rr += 8)
        dst[(size_t)(n0 + ty + rr) * ND + k0 + tx] = f2bf(tile[tx][ty + rr]);
}

// --- z-fused QKV GEMM ------------------------------------------------------
// Grid (32,16): m0 = bx*128, n0 = by*64. 256 threads = 4 waves (2M x 2N),
// wave owns 64x32 per z. BK=64. A staged once + 3 B tiles per K-step.
// Vt epilogue stores row s at kv-permuted column (pi^-1 within 64-block).
__global__ __launch_bounds__(256) void qkv_gemm_k(const u16* __restrict__ xb,
                                                  const u16* __restrict__ wt,
                                                  u16* __restrict__ qh,
                                                  u16* __restrict__ kh,
                                                  u16* __restrict__ vt) {
    __shared__ u16 At[128 * 64];     // 16 KiB
    __shared__ u16 Bt[3][64 * 64];   // 3 x 8 KiB
    const int m0 = blockIdx.x * 128;
    const int n0 = blockIdx.y * 64;
    const int t = threadIdx.x;
    const int lane = t & 63;
    const int wv = t >> 6;
    const int wm = (wv >> 1) * 64, wn = (wv & 1) * 32;
    const int fr = lane & 15;
    const int ks = lane >> 4;

    f32x4 acc[3][4][2] = {};

    for (int kt = 0; kt < ND; kt += 64) {
#pragma unroll
        for (int c = 0; c < 4; c++) {
            const int L = c * 4096 + t * 16;
            const int row = L >> 7;
            const int cb = (L & 127) ^ ((row & 7) << 4);
            gl_lds16((const char*)xb + (size_t)(m0 + row) * 2048 + kt * 2 + cb,
                     (char*)At + L);
        }
#pragma unroll
        for (int z = 0; z < 3; z++)
#pragma unroll
            for (int c = 0; c < 2; c++) {
                const int L = c * 4096 + t * 16;
                const int row = L >> 7;  // 0..63
                const int cb = (L & 127) ^ ((row & 7) << 4);
                gl_lds16((const char*)wt + (size_t)z * (ND * ND * 2) +
                             (size_t)(n0 + row) * 2048 + kt * 2 + cb,
                         (char*)&Bt[z][0] + L);
            }
        __syncthreads();

        bf16x8 fa[4][2];
#pragma unroll
        for (int i = 0; i < 4; i++)
#pragma unroll
            for (int c = 0; c < 2; c++)
                fa[i][c] = ldsw(At, wm + i * 16 + fr, c * 64 + ks * 16);

#pragma unroll
        for (int z = 0; z < 3; z++) {
            bf16x8 fb[2][2];
#pragma unroll
            for (int j = 0; j < 2; j++)
#pragma unroll
                for (int c = 0; c < 2; c++)
                    fb[j][c] =
                        ldsw(&Bt[z][0], wn + j * 16 + fr, c * 64 + ks * 16);
            if (z < 2) {
#pragma unroll
                for (int i = 0; i < 4; i++)
#pragma unroll
                    for (int j = 0; j < 2; j++)
#pragma unroll
                        for (int c = 0; c < 2; c++)
                            acc[z][i][j] =
                                mfma16(fa[i][c], fb[j][c], acc[z][i][j]);
            } else {
#pragma unroll
                for (int i = 0; i < 4; i++)
#pragma unroll
                    for (int j = 0; j < 2; j++)
#pragma unroll
                        for (int c = 0; c < 2; c++)
                            acc[z][i][j] =
                                mfma16(fb[j][c], fa[i][c], acc[z][i][j]);
            }
        }
        __syncthreads();
    }

#pragma unroll
    for (int z = 0; z < 2; z++) {
        u16* dst = (z == 0) ? qh : kh;
#pragma unroll
        for (int i = 0; i < 4; i++)
#pragma unroll
            for (int j = 0; j < 2; j++)
#pragma unroll
                for (int r = 0; r < 4; r++) {
                    int mg = m0 + wm + i * 16 + ks * 4 + r;
                    int ng = n0 + wn + j * 16 + fr;
                    int b = mg >> 11, s = mg & 2047;
                    int hh = ng >> 6, dd = ng & 63;
                    dst[(((size_t)b * NH + hh) * NS + s) * HD + dd] =
                        f2bf(acc[z][i][j][r]);
                }
    }
#pragma unroll
    for (int i = 0; i < 4; i++)
#pragma unroll
        for (int j = 0; j < 2; j++)
#pragma unroll
            for (int r = 0; r < 4; r++) {
                int ng = n0 + wn + j * 16 + ks * 4 + r;  // d-dim
                int mg = m0 + wm + i * 16 + fr;          // s-dim (kv)
                int b = mg >> 11, s = mg & 2047;
                int hh = ng >> 6, dd = ng & 63;
                // pi^-1 within the 64-block: w -> (w&32)|ks'<<3|kf0<<2|r'
                int w = s & 63;
                int sp = (s & ~63) | (w & 32) | (((w >> 2) & 3) << 3) |
                         (((w >> 4) & 1) << 2) | (w & 3);
                vt[(((size_t)b * NH + hh) * HD + dd) * NS + sp] =
                    f2bf(acc[2][i][j][r]);
            }
}

// --- causal flash attention ------------------------------------------------
// 512 blocks x 256 threads (4 waves). bh = blk&31 (XCD-affine), p = blk>>5.
// Block handles q-tiles A=31-p (heavy) and B=p (light): uniform 33 KV-iters.
// K,V 64-row tiles staged in LDS (dbuf, swizzled). Swapped QK^T gives
// S^T[kv=16kf+4ks+r][q=fr] in registers; kv-permutation pi (baked into the
// V^T layout by the GEMM) makes pa[s2][(kf&1)*4+r] = bf16(exp(sc[kf][r]))
// the exact PV A-fragment -- NO P LDS round-trip. Fixed-ref-max softmax
// p = exp2(fma(s, 0.125*log2e, -8*log2e)); row-sum via all-ones MFMA.

__device__ __forceinline__ void stage_kv(const u16* __restrict__ K,
                                         const u16* __restrict__ V, int kv0,
                                         u16* Kl, u16* Vl, int t) {
#pragma unroll
    for (int c = 0; c < 2; c++) {
        const int L = c * 4096 + t * 16;
        const int row = L >> 7;
        const int cb = (L & 127) ^ ((row & 7) << 4);
        gl_lds16((const char*)K + (size_t)(kv0 + row) * 128 + cb,
                 (char*)Kl + L);
        gl_lds16((const char*)V + (size_t)row * (NS * 2) + kv0 * 2 + cb,
                 (char*)Vl + L);
    }
}

// sc = S^T fragments -> pa (PV A-operand) entirely in registers
template <bool MASKED>
__device__ __forceinline__ void sm_pack(const f32x4* sc, bf16x8 pa[2],
                                        int kv0, int q0, int fr, int ks) {
    const int qg = q0 + fr;
#pragma unroll
    for (int kf = 0; kf < 4; kf++)
#pragma unroll
        for (int r = 0; r < 4; r++) {
            float s = sc[kf][r];
            if (MASKED && (kv0 + kf * 16 + ks * 4 + r > qg)) s = -3.0e38f;
            // exp(s/8 - 8) == exp2(s*0.125*log2e - 8*log2e)
            pa[kf >> 1][(kf & 1) * 4 + r] =
                (__bf16)exp2f(fmaf(s, 0.18033688f, -11.5415603f));
        }
}

__device__ __forceinline__ void pv_reg(const bf16x8 (*fv)[2],
                                       const bf16x8 pa[2], f32x4* o,
                                       f32x4& lacc, bf16x8 ones) {
    __builtin_amdgcn_s_setprio(1);
    lacc = mfma16(pa[0], ones, lacc);
    lacc = mfma16(pa[1], ones, lacc);
#pragma unroll
    for (int j = 0; j < 4; j++)
#pragma unroll
        for (int s2 = 0; s2 < 2; s2++) o[j] = mfma16(pa[s2], fv[j][s2], o[j]);
    __builtin_amdgcn_s_setprio(0);
}

__global__ __launch_bounds__(256, 2) void attn_k(const u16* __restrict__ qh,
                                                 const u16* __restrict__ kh,
                                                 const u16* __restrict__ vt,
                                                 float* __restrict__ out) {
    const int t = threadIdx.x, lane = t & 63, wv = t >> 6;
    const int fr = lane & 15, ks = lane >> 4;
    const int bh = blockIdx.x & 31;
    const int p = blockIdx.x >> 5;  // 0..15
    const int b = bh >> 4, h = bh & 15;
    const int tileA = 31 - p, tileB = p;
    const int qA = tileA * 64 + wv * 16;
    const int qB = tileB * 64 + wv * 16;
    const int nA = tileA + 1, nB = tileB + 1;
    const u16* Q = qh + (size_t)bh * NS * HD;
    const u16* K = kh + (size_t)bh * NS * HD;
    const u16* V = vt + (size_t)bh * HD * NS;

    __shared__ u16 Kl[2][64 * 64];  // 16 KiB dbuf
    __shared__ u16 Vl[2][64 * 64];  // 16 KiB dbuf

    bf16x8 fqA[2], fqB[2];
#pragma unroll
    for (int sl = 0; sl < 2; sl++) {
        fqA[sl] = *(const bf16x8*)&Q[(qA + fr) * HD + sl * 32 + ks * 8];
        fqB[sl] = *(const bf16x8*)&Q[(qB + fr) * HD + sl * 32 + ks * 8];
    }

    u16x8 ob;
#pragma unroll
    for (int j = 0; j < 8; j++) ob[j] = 0x3F80;  // bf16 1.0
    const bf16x8 ones = __builtin_bit_cast(bf16x8, ob);

    f32x4 oA[4] = {}, oB[4] = {};
    f32x4 lA = {}, lB = {};

    stage_kv(K, V, 0, &Kl[0][0], &Vl[0][0], t);
    __syncthreads();

    for (int it = 0; it < nA; ++it) {
        const int cur = it & 1;
        const int kv0 = it * 64;
        if (it + 1 < nA)
            stage_kv(K, V, kv0 + 64, &Kl[cur ^ 1][0], &Vl[cur ^ 1][0], t);

        bf16x8 fk[4][2];
#pragma unroll
        for (int kf = 0; kf < 4; kf++)
#pragma unroll
            for (int sl = 0; sl < 2; sl++)
                fk[kf][sl] =
                    ldsw(&Kl[cur][0], kf * 16 + fr, sl * 64 + ks * 16);

        // swapped QK^T: sc = S^T fragments
        f32x4 scA[4] = {}, scB[4] = {};
        const bool doB = it < nB;
        __builtin_amdgcn_s_setprio(1);
#pragma unroll
        for (int kf = 0; kf < 4; kf++) {
            scA[kf] = mfma16(fk[kf][0], fqA[0], scA[kf]);
            scA[kf] = mfma16(fk[kf][1], fqA[1], scA[kf]);
        }
        if (doB) {
#pragma unroll
            for (int kf = 0; kf < 4; kf++) {
                scB[kf] = mfma16(fk[kf][0], fqB[0], scB[kf]);
                scB[kf] = mfma16(fk[kf][1], fqB[1], scB[kf]);
            }
        }
        __builtin_amdgcn_s_setprio(0);

        bf16x8 fv[4][2];
#pragma unroll
        for (int j = 0; j < 4; j++)
#pragma unroll
            for (int s2 = 0; s2 < 2; s2++)
                fv[j][s2] =
                    ldsw(&Vl[cur][0], j * 16 + fr, s2 * 64 + ks * 16);

        bf16x8 paA[2], paB[2];
        if (it == nA - 1)
            sm_pack<true>(scA, paA, kv0, qA, fr, ks);
        else
            sm_pack<false>(scA, paA, kv0, qA, fr, ks);
        pv_reg(fv, paA, oA, lA, ones);

        if (doB) {
            if (it == nB - 1)
                sm_pack<true>(scB, paB, kv0, qB, fr, ks);
            else
                sm_pack<false>(scB, paB, kv0, qB, fr, ks);
            pv_reg(fv, paB, oB, lB, ones);
        }

        __syncthreads();
    }

    float rlA[4], rlB[4];
#pragma unroll
    for (int r = 0; r < 4; r++) {
        rlA[r] = 1.0f / lA[r];
        rlB[r] = 1.0f / lB[r];
    }
#pragma unroll
    for (int j = 0; j < 4; j++)
#pragma unroll
        for (int r = 0; r < 4; r++) {
            const int qgA = qA + ks * 4 + r;
            const int qgB = qB + ks * 4 + r;
            out[((size_t)b * NS + qgA) * ND + h * HD + j * 16 + fr] =
                oA[j][r] * rlA[r];
            out[((size_t)b * NS + qgB) * ND + h * HD + j * 16 + fr] =
                oB[j][r] * rlB[r];
        }
}

extern "C" void kernel_launch(void* const* d_in, const int* in_sizes, int n_in,
                              void* d_out, int out_size, void* d_ws,
                              size_t ws_size, hipStream_t stream) {
    const float* x = (const float*)d_in[0];
    const float* wq = (const float*)d_in[1];
    const float* wk = (const float*)d_in[2];
    const float* wvp = (const float*)d_in[3];
    float* out = (float*)d_out;

    char* w8 = (char*)d_ws;
    u16* xb = (u16*)(w8);                      // 8 MiB
    u16* wt = (u16*)(w8 + ((size_t)8 << 20));  // 6 MiB
    u16* qh = (u16*)(w8 + ((size_t)14 << 20));
    u16* kh = (u16*)(w8 + ((size_t)22 << 20));
    u16* vt = (u16*)(w8 + ((size_t)30 << 20));

    convx_k<<<(NB * NS * ND) / (256 * 8), 256, 0, stream>>>(x, xb);
    convw_k<<<dim3(ND / 32, ND / 32, 3), 256, 0, stream>>>(wq, wk, wvp, wt);
    qkv_gemm_k<<<dim3((NB * NS) / 128, ND / 64), 256, 0, stream>>>(
        xb, wt, qh, kh, vt);
    attn_k<<<512, 256, 0, stream>>>(qh, kh, vt, out);
}